// Round 1
// baseline (405.752 us; speedup 1.0000x reference)
//
#include <hip/hip_runtime.h>
#include <hip/hip_bf16.h>
#include <stdint.h>

#define SEQLEN   1024
#define DMODEL   2048
#define DINNER   4096
#define NHEADS   64
#define HEADDIM  64
#define DSTATE   64
#define CONVDIM  4224
#define DINPROJ  8384
#define RMS_EPS  1e-5f

typedef __attribute__((ext_vector_type(8))) __bf16 bf16x8;
typedef __attribute__((ext_vector_type(4))) float f32x4;

__device__ __forceinline__ ushort f2bf(float f) {
    uint32_t u = __float_as_uint(f);
    u += 0x7FFFu + ((u >> 16) & 1u);   // round-to-nearest-even
    return (ushort)(u >> 16);
}

// ---------------------------------------------------------------- cvt f32->bf16
__global__ __launch_bounds__(256) void cvt_kernel(const float* __restrict__ in,
                                                  ushort* __restrict__ out, int n4) {
    int i = blockIdx.x * 256 + threadIdx.x;
    if (i < n4) {
        float4 v = ((const float4*)in)[i];
        ushort4 o;
        o.x = f2bf(v.x); o.y = f2bf(v.y); o.z = f2bf(v.z); o.w = f2bf(v.w);
        ((ushort4*)out)[i] = o;
    }
}

// ---------------------------------------------------------------- bf16 MFMA GEMM
// C[M,N] = A[M,K] * B[N,K]^T   (both row-major, K contiguous). M%128==0, K%64==0.
// 128x128 tile, BK=64, 4 waves (2x2), each wave 64x64 via 4x4 16x16x32 MFMA frags.
__global__ __launch_bounds__(256) void gemm_bf16_nt(
    const __bf16* __restrict__ A, const __bf16* __restrict__ B,
    float* __restrict__ C, int M, int N, int K)
{
    __shared__ __align__(16) __bf16 As[128 * 64];
    __shared__ __align__(16) __bf16 Bs[128 * 64];
    const int tid  = threadIdx.x;
    const int lane = tid & 63;
    const int wave = tid >> 6;
    const int wr = wave >> 1, wc = wave & 1;
    const int row0 = blockIdx.y * 128, col0 = blockIdx.x * 128;
    const int lr = lane & 15, lq = lane >> 4;

    f32x4 acc[4][4] = {};

    for (int k0 = 0; k0 < K; k0 += 64) {
        __syncthreads();
        #pragma unroll
        for (int pass = 0; pass < 4; ++pass) {
            int g  = pass * 256 + tid;
            int r  = g >> 3, kg = g & 7;
            int sw = (kg ^ (r & 7)) * 8;          // XOR swizzle: 16B slots within row
            int4 va = *(const int4*)(A + (size_t)(row0 + r) * K + k0 + kg * 8);
            *(int4*)(As + r * 64 + sw) = va;
            int gb = col0 + r; if (gb >= N) gb = N - 1;   // clamp ragged N tile
            int4 vb = *(const int4*)(B + (size_t)gb * K + k0 + kg * 8);
            *(int4*)(Bs + r * 64 + sw) = vb;
        }
        __syncthreads();
        #pragma unroll
        for (int kk = 0; kk < 2; ++kk) {
            const int kg = kk * 4 + lq;
            bf16x8 af[4], bfr[4];
            #pragma unroll
            for (int m = 0; m < 4; ++m) {
                int r = wr * 64 + m * 16 + lr;
                af[m] = *(const bf16x8*)(As + r * 64 + ((kg ^ (r & 7)) * 8));
            }
            #pragma unroll
            for (int n = 0; n < 4; ++n) {
                int r = wc * 64 + n * 16 + lr;
                bfr[n] = *(const bf16x8*)(Bs + r * 64 + ((kg ^ (r & 7)) * 8));
            }
            #pragma unroll
            for (int m = 0; m < 4; ++m)
                #pragma unroll
                for (int n = 0; n < 4; ++n)
                    acc[m][n] = __builtin_amdgcn_mfma_f32_16x16x32_bf16(af[m], bfr[n], acc[m][n], 0, 0, 0);
        }
    }
    // epilogue: C/D layout col=lane&15, row=(lane>>4)*4+j
    #pragma unroll
    for (int m = 0; m < 4; ++m)
        #pragma unroll
        for (int n = 0; n < 4; ++n) {
            int col = col0 + wc * 64 + n * 16 + lr;
            if (col < N) {
                #pragma unroll
                for (int j = 0; j < 4; ++j) {
                    int row = row0 + wr * 64 + m * 16 + lq * 4 + j;
                    C[(size_t)row * N + col] = acc[m][n][j];
                }
            }
        }
}

// ---------------------------------------------------------------- conv + dt/dA
__global__ __launch_bounds__(256) void conv_dt_kernel(
    const float* __restrict__ zx,       // [1024][8384]
    const float* __restrict__ conv_w,   // [4224][4]
    const float* __restrict__ conv_b,   // [4224]
    const float* __restrict__ dt_bias,  // [64]
    const float* __restrict__ A_log,    // [64]
    float* __restrict__ x_scan,         // [1024][4096]
    float* __restrict__ Bb,             // [1024][64]
    float* __restrict__ Cb,             // [1024][64]
    float* __restrict__ dtb,            // [1024][64]
    float* __restrict__ dAb)            // [1024][64]
{
    int t = blockIdx.y;
    int c = blockIdx.x * 256 + threadIdx.x;
    if (c >= CONVDIM + NHEADS) return;
    if (c < CONVDIM) {
        float acc = conv_b[c];
        #pragma unroll
        for (int k = 0; k < 4; ++k) {
            int tt = t + k - 3;
            if (tt >= 0) acc += zx[(size_t)tt * DINPROJ + DINNER + c] * conv_w[c * 4 + k];
        }
        float s = acc / (1.f + __expf(-acc));    // silu
        if (c < DINNER)            x_scan[(size_t)t * DINNER + c] = s;
        else if (c < DINNER + 64)  Bb[t * 64 + (c - DINNER)] = s;
        else                       Cb[t * 64 + (c - DINNER - 64)] = s;
    } else {
        int h = c - CONVDIM;
        float raw = zx[(size_t)t * DINPROJ + (DINNER + CONVDIM) + h] + dt_bias[h];
        float dt = (raw > 20.f) ? raw : log1pf(__expf(raw));
        float A  = -__expf(A_log[h]);
        dtb[t * 64 + h] = dt;
        dAb[t * 64 + h] = __expf(dt * A);
    }
}

// ---------------------------------------------------------------- selective scan
// 128 blocks = 64 heads x 2 n-chunks (32 states each). 256 threads: p = tid>>2 (0..63),
// q = tid&3 handles 8 n's. h state in registers; 64-step LDS tiles.
__global__ __launch_bounds__(256) void scan_kernel(
    const float* __restrict__ x_scan, const float* __restrict__ Bb,
    const float* __restrict__ Cb, const float* __restrict__ dtb,
    const float* __restrict__ dAb, float* __restrict__ ypart)
{
    const int head  = blockIdx.x >> 1;
    const int chunk = blockIdx.x & 1;
    const int tid = threadIdx.x;
    const int p = tid >> 2, q = tid & 3;

    __shared__ float xs[64][64];
    __shared__ float Bs[64][32];
    __shared__ float Cs[64][32];
    __shared__ float dAs[64], dts[64];

    float h[8] = {0, 0, 0, 0, 0, 0, 0, 0};

    for (int t0 = 0; t0 < SEQLEN; t0 += 64) {
        __syncthreads();
        #pragma unroll
        for (int pass = 0; pass < 4; ++pass) {          // x tile: 64x64 f32
            int r = pass * 16 + (tid >> 4);
            int c = (tid & 15) * 4;
            *(float4*)&xs[r][c] = *(const float4*)&x_scan[(size_t)(t0 + r) * DINNER + head * 64 + c];
        }
        #pragma unroll
        for (int pass = 0; pass < 2; ++pass) {          // B,C tiles: 64x32 f32
            int g = pass * 256 + tid;
            int r = g >> 3, c = (g & 7) * 4;
            *(float4*)&Bs[r][c] = *(const float4*)&Bb[(t0 + r) * 64 + chunk * 32 + c];
            *(float4*)&Cs[r][c] = *(const float4*)&Cb[(t0 + r) * 64 + chunk * 32 + c];
        }
        if (tid < 64) {
            dAs[tid] = dAb[(t0 + tid) * 64 + head];
            dts[tid] = dtb[(t0 + tid) * 64 + head];
        }
        __syncthreads();
        #pragma unroll 2
        for (int tt = 0; tt < 64; ++tt) {
            float da  = dAs[tt];
            float dtx = dts[tt] * xs[tt][p];
            float4 b0 = *(const float4*)&Bs[tt][q * 8];
            float4 b1 = *(const float4*)&Bs[tt][q * 8 + 4];
            float4 c0 = *(const float4*)&Cs[tt][q * 8];
            float4 c1 = *(const float4*)&Cs[tt][q * 8 + 4];
            float acc;
            h[0] = h[0] * da + dtx * b0.x; acc  = h[0] * c0.x;
            h[1] = h[1] * da + dtx * b0.y; acc += h[1] * c0.y;
            h[2] = h[2] * da + dtx * b0.z; acc += h[2] * c0.z;
            h[3] = h[3] * da + dtx * b0.w; acc += h[3] * c0.w;
            h[4] = h[4] * da + dtx * b1.x; acc += h[4] * c1.x;
            h[5] = h[5] * da + dtx * b1.y; acc += h[5] * c1.y;
            h[6] = h[6] * da + dtx * b1.z; acc += h[6] * c1.z;
            h[7] = h[7] * da + dtx * b1.w; acc += h[7] * c1.w;
            acc += __shfl_xor(acc, 1, 64);
            acc += __shfl_xor(acc, 2, 64);
            if (q == 0)
                ypart[(size_t)chunk * SEQLEN * DINNER + (size_t)(t0 + tt) * DINNER + head * 64 + p] = acc;
        }
    }
}

// ---------------------------------------------------------------- combine + gate + RMSNorm
__global__ __launch_bounds__(256) void combine_norm_kernel(
    const float* __restrict__ ypart, const float* __restrict__ x_scan,
    const float* __restrict__ zx, const float* __restrict__ Dv,
    const float* __restrict__ norm_w, ushort* __restrict__ ybf)
{
    const int t = blockIdx.x;
    const int tid = threadIdx.x;
    float yv[16];
    float ss = 0.f;
    #pragma unroll
    for (int j = 0; j < 16; ++j) {
        int i = j * 256 + tid;
        float y = ypart[(size_t)t * DINNER + i]
                + ypart[(size_t)SEQLEN * DINNER + (size_t)t * DINNER + i]
                + Dv[i >> 6] * x_scan[(size_t)t * DINNER + i];
        float z = zx[(size_t)t * DINPROJ + i];
        y *= z / (1.f + __expf(-z));             // y * silu(z)
        yv[j] = y;
        ss += y * y;
    }
    #pragma unroll
    for (int off = 1; off < 64; off <<= 1) ss += __shfl_xor(ss, off, 64);
    __shared__ float red[4];
    if ((tid & 63) == 0) red[tid >> 6] = ss;
    __syncthreads();
    float total = red[0] + red[1] + red[2] + red[3];
    float scale = rsqrtf(total * (1.f / DINNER) + RMS_EPS);
    #pragma unroll
    for (int j = 0; j < 16; ++j) {
        int i = j * 256 + tid;
        ybf[(size_t)t * DINNER + i] = f2bf(yv[j] * scale * norm_w[i]);
    }
}

// ---------------------------------------------------------------- launch
extern "C" void kernel_launch(void* const* d_in, const int* in_sizes, int n_in,
                              void* d_out, int out_size, void* d_ws, size_t ws_size,
                              hipStream_t stream)
{
    const float* x       = (const float*)d_in[0];
    const float* W_in    = (const float*)d_in[1];
    const float* conv_w  = (const float*)d_in[2];
    const float* conv_b  = (const float*)d_in[3];
    const float* dt_bias = (const float*)d_in[4];
    const float* A_log   = (const float*)d_in[5];
    const float* Dv      = (const float*)d_in[6];
    const float* norm_w  = (const float*)d_in[7];
    const float* W_out   = (const float*)d_in[8];
    float* out = (float*)d_out;

    char* ws = (char*)d_ws;
    // layout (bytes). ypart aliases W_in_bf (dead after gemm1).
    const size_t OFF_WIN  = 0;                              // 34,340,864 (bf16 W_in)  / later ypart 33,554,432
    const size_t OFF_WOUT = 34340864;                       // 16,777,216 (bf16 W_out)
    const size_t OFF_XBF  = OFF_WOUT + 16777216;            //  4,194,304 (bf16 x)
    const size_t OFF_ZX   = OFF_XBF + 4194304;              // 34,340,864 (f32 zxbcdt)
    const size_t OFF_XSC  = OFF_ZX + 34340864;              // 16,777,216 (f32 x_scan)
    const size_t OFF_BB   = OFF_XSC + 16777216;             //    262,144
    const size_t OFF_CB   = OFF_BB + 262144;
    const size_t OFF_DT   = OFF_CB + 262144;
    const size_t OFF_DA   = OFF_DT + 262144;
    const size_t OFF_YBF  = OFF_DA + 262144;                //  8,388,608 (bf16 y)

    ushort* WinBf  = (ushort*)(ws + OFF_WIN);
    ushort* WoutBf = (ushort*)(ws + OFF_WOUT);
    ushort* xBf    = (ushort*)(ws + OFF_XBF);
    float*  zxb    = (float*)(ws + OFF_ZX);
    float*  xsc    = (float*)(ws + OFF_XSC);
    float*  Bb     = (float*)(ws + OFF_BB);
    float*  Cb     = (float*)(ws + OFF_CB);
    float*  dtb    = (float*)(ws + OFF_DT);
    float*  dAb    = (float*)(ws + OFF_DA);
    ushort* ybf    = (ushort*)(ws + OFF_YBF);
    float*  ypart  = (float*)(ws + OFF_WIN);                // alias

    int n4;
    n4 = DINPROJ * DMODEL / 4;
    cvt_kernel<<<(n4 + 255) / 256, 256, 0, stream>>>(W_in, WinBf, n4);
    n4 = DMODEL * DINNER / 4;
    cvt_kernel<<<(n4 + 255) / 256, 256, 0, stream>>>(W_out, WoutBf, n4);
    n4 = SEQLEN * DMODEL / 4;
    cvt_kernel<<<(n4 + 255) / 256, 256, 0, stream>>>(x, xBf, n4);

    gemm_bf16_nt<<<dim3((DINPROJ + 127) / 128, SEQLEN / 128), 256, 0, stream>>>(
        (const __bf16*)xBf, (const __bf16*)WinBf, zxb, SEQLEN, DINPROJ, DMODEL);

    conv_dt_kernel<<<dim3(17, SEQLEN), 256, 0, stream>>>(
        zxb, conv_w, conv_b, dt_bias, A_log, xsc, Bb, Cb, dtb, dAb);

    scan_kernel<<<128, 256, 0, stream>>>(xsc, Bb, Cb, dtb, dAb, ypart);

    combine_norm_kernel<<<SEQLEN, 256, 0, stream>>>(ypart, xsc, zxb, Dv, norm_w, ybf);

    gemm_bf16_nt<<<dim3(DMODEL / 128, SEQLEN / 128), 256, 0, stream>>>(
        (const __bf16*)ybf, (const __bf16*)WoutBf, out, SEQLEN, DMODEL, DINNER);
}

// Round 2
// 278.685 us; speedup vs baseline: 1.4560x; 1.4560x over previous
//
#include <hip/hip_runtime.h>
#include <hip/hip_bf16.h>
#include <stdint.h>

#define SEQLEN   1024
#define DMODEL   2048
#define DINNER   4096
#define NHEADS   64
#define HEADDIM  64
#define DSTATE   64
#define CONVDIM  4224
#define DINPROJ  8384
#define RMS_EPS  1e-5f
#define CPAD     68

typedef __attribute__((ext_vector_type(8))) __bf16 bf16x8;
typedef __attribute__((ext_vector_type(4))) float f32x4;

__device__ __forceinline__ ushort f2bf(float f) {
    uint32_t u = __float_as_uint(f);
    u += 0x7FFFu + ((u >> 16) & 1u);   // round-to-nearest-even
    return (ushort)(u >> 16);
}

__device__ __forceinline__ void gload_lds16(const void* g, void* l) {
    __builtin_amdgcn_global_load_lds(
        (const __attribute__((address_space(1))) void*)g,
        (__attribute__((address_space(3))) void*)l, 16, 0, 0);
}

// ---------------------------------------------------------------- cvt f32->bf16
__global__ __launch_bounds__(256) void cvt_kernel(const float* __restrict__ in,
                                                  ushort* __restrict__ out, int n4) {
    int i = blockIdx.x * 256 + threadIdx.x;
    if (i < n4) {
        float4 v = ((const float4*)in)[i];
        ushort4 o;
        o.x = f2bf(v.x); o.y = f2bf(v.y); o.z = f2bf(v.z); o.w = f2bf(v.w);
        ((ushort4*)out)[i] = o;
    }
}

// ---------------------------------------------------------------- bf16 MFMA GEMM
// C[M,N] = A[M,K] * B[N,K]^T. 128x128 tile, BK=64, 4 waves, global_load_lds staging.
// LDS linear [r][j]; slot j of row r holds global k-chunk (j ^ (r&7)) (pre-swizzled src).
__global__ __launch_bounds__(256) void gemm_bf16_nt(
    const __bf16* __restrict__ A, const __bf16* __restrict__ B,
    float* __restrict__ C, int M, int N, int K)
{
    __shared__ __align__(16) __bf16 As[128 * 64];
    __shared__ __align__(16) __bf16 Bs[128 * 64];
    const int tid  = threadIdx.x;
    const int lane = tid & 63;
    const int wave = tid >> 6;
    const int wr = wave >> 1, wc = wave & 1;
    const int row0 = blockIdx.y * 128, col0 = blockIdx.x * 128;
    const int lr = lane & 15, lq = lane >> 4;
    const int rA = lane >> 3, jl = lane & 7;

    f32x4 acc[4][4] = {};

    for (int k0 = 0; k0 < K; k0 += 64) {
        __syncthreads();
        #pragma unroll
        for (int e = 0; e < 4; ++e) {
            int r0 = (wave * 4 + e) * 8;
            int r  = r0 + rA;
            int jg = jl ^ (r & 7);
            gload_lds16(A + (size_t)(row0 + r) * K + k0 + jg * 8, As + r0 * 64);
            int gb = col0 + r; if (gb > N - 1) gb = N - 1;
            gload_lds16(B + (size_t)gb * K + k0 + jg * 8, Bs + r0 * 64);
        }
        __syncthreads();
        #pragma unroll
        for (int kk = 0; kk < 2; ++kk) {
            const int kg = kk * 4 + lq;
            bf16x8 af[4], bfr[4];
            #pragma unroll
            for (int m = 0; m < 4; ++m) {
                int r = wr * 64 + m * 16 + lr;
                af[m] = *(const bf16x8*)(As + r * 64 + ((kg ^ (r & 7)) * 8));
            }
            #pragma unroll
            for (int n = 0; n < 4; ++n) {
                int r = wc * 64 + n * 16 + lr;
                bfr[n] = *(const bf16x8*)(Bs + r * 64 + ((kg ^ (r & 7)) * 8));
            }
            #pragma unroll
            for (int m = 0; m < 4; ++m)
                #pragma unroll
                for (int n = 0; n < 4; ++n)
                    acc[m][n] = __builtin_amdgcn_mfma_f32_16x16x32_bf16(af[m], bfr[n], acc[m][n], 0, 0, 0);
        }
    }
    #pragma unroll
    for (int m = 0; m < 4; ++m)
        #pragma unroll
        for (int n = 0; n < 4; ++n) {
            int col = col0 + wc * 64 + n * 16 + lr;
            if (col < N) {
                #pragma unroll
                for (int j = 0; j < 4; ++j) {
                    int row = row0 + wr * 64 + m * 16 + lq * 4 + j;
                    C[(size_t)row * N + col] = acc[m][n][j];
                }
            }
        }
}

// ---------------------------------------------------------------- conv + dt/dtA
__global__ __launch_bounds__(256) void conv_dt_kernel(
    const float* __restrict__ zx, const float* __restrict__ conv_w,
    const float* __restrict__ conv_b, const float* __restrict__ dt_bias,
    const float* __restrict__ A_log,
    float* __restrict__ x_scan, float* __restrict__ Bb, float* __restrict__ Cb,
    float* __restrict__ dtb, float* __restrict__ dtAb)
{
    int t = blockIdx.y;
    int c = blockIdx.x * 256 + threadIdx.x;
    if (c >= CONVDIM + NHEADS) return;
    if (c < CONVDIM) {
        float acc = conv_b[c];
        #pragma unroll
        for (int k = 0; k < 4; ++k) {
            int tt = t + k - 3;
            if (tt >= 0) acc += zx[(size_t)tt * DINPROJ + DINNER + c] * conv_w[c * 4 + k];
        }
        float s = acc / (1.f + __expf(-acc));
        if (c < DINNER)            x_scan[(size_t)t * DINNER + c] = s;
        else if (c < DINNER + 64)  Bb[t * 64 + (c - DINNER)] = s;
        else                       Cb[t * 64 + (c - DINNER - 64)] = s;
    } else {
        int h = c - CONVDIM;
        float raw = zx[(size_t)t * DINPROJ + (DINNER + CONVDIM) + h] + dt_bias[h];
        float dt = (raw > 20.f) ? raw : log1pf(__expf(raw));
        dtb[t * 64 + h]  = dt;
        dtAb[t * 64 + h] = dt * (-__expf(A_log[h]));
    }
}

// ---------------------------------------------------------------- chunked scan A: intra-chunk
// block = (head, chunk of 64 t). Computes Y_intra, T_c, Ssum.
__global__ __launch_bounds__(256) void chunk_intra_kernel(
    const float* __restrict__ x_scan, const float* __restrict__ Bb,
    const float* __restrict__ Cb, const float* __restrict__ dtb,
    const float* __restrict__ dtAb,
    float* __restrict__ yintra, float* __restrict__ Tc, float* __restrict__ Ssum)
{
    const int head  = blockIdx.x >> 4;
    const int chunk = blockIdx.x & 15;
    const int t0 = chunk * 64;
    const int tid = threadIdx.x;
    const int ty = tid >> 4, tx = tid & 15;
    const int lane = tid & 63, wv = tid >> 6;

    __shared__ __align__(16) float Xs [64][CPAD];   // [s][p]
    __shared__ __align__(16) float BsT[64][CPAD];   // [n][s]
    __shared__ __align__(16) float CsT[64][CPAD];   // [n][i] -> reused as Bs2[s][n]
    __shared__ __align__(16) float GsT[64][CPAD];   // [s][i]
    __shared__ float Sc[64], dts[64], ws[64];

    // stage X (direct), B/C (transposed, conflict-free writes)
    #pragma unroll
    for (int pass = 0; pass < 4; ++pass) {
        int r = pass * 16 + ty;
        *(float4*)&Xs[r][tx * 4] =
            *(const float4*)&x_scan[(size_t)(t0 + r) * DINNER + head * 64 + tx * 4];
    }
    #pragma unroll
    for (int k = 0; k < 4; ++k) {
        int n0 = wv * 16 + k * 4;
        float4 b = *(const float4*)&Bb[(t0 + lane) * 64 + n0];
        float4 c = *(const float4*)&Cb[(t0 + lane) * 64 + n0];
        BsT[n0][lane] = b.x; BsT[n0+1][lane] = b.y; BsT[n0+2][lane] = b.z; BsT[n0+3][lane] = b.w;
        CsT[n0][lane] = c.x; CsT[n0+1][lane] = c.y; CsT[n0+2][lane] = c.z; CsT[n0+3][lane] = c.w;
    }
    if (tid < 64) dts[tid] = dtb[(t0 + tid) * 64 + head];
    if (wv == 1) {   // wave 1: prefix-sum of dt*A (log decay)
        float v = dtAb[(t0 + lane) * 64 + head];
        #pragma unroll
        for (int off = 1; off < 64; off <<= 1) {
            float u = __shfl_up(v, off, 64);
            if (lane >= off) v += u;
        }
        Sc[lane] = v;
        Ssum[(t0 + lane) * 64 + head] = v;
    }
    __syncthreads();
    if (tid < 64) ws[tid] = dts[tid] * __expf(Sc[63] - Sc[tid]);

    // G[i][s] = (C_i . B_s) -> scale dt_s * exp(S_i - S_s), mask s<=i, store GsT[s][i]
    float gacc[4][4] = {};
    for (int n = 0; n < 64; ++n) {
        float4 ci = *(const float4*)&CsT[n][ty * 4];
        float4 bs = *(const float4*)&BsT[n][tx * 4];
        gacc[0][0] += ci.x*bs.x; gacc[0][1] += ci.x*bs.y; gacc[0][2] += ci.x*bs.z; gacc[0][3] += ci.x*bs.w;
        gacc[1][0] += ci.y*bs.x; gacc[1][1] += ci.y*bs.y; gacc[1][2] += ci.y*bs.z; gacc[1][3] += ci.y*bs.w;
        gacc[2][0] += ci.z*bs.x; gacc[2][1] += ci.z*bs.y; gacc[2][2] += ci.z*bs.z; gacc[2][3] += ci.z*bs.w;
        gacc[3][0] += ci.w*bs.x; gacc[3][1] += ci.w*bs.y; gacc[3][2] += ci.w*bs.z; gacc[3][3] += ci.w*bs.w;
    }
    {
        float Si[4];
        #pragma unroll
        for (int di = 0; di < 4; ++di) Si[di] = Sc[ty * 4 + di];
        #pragma unroll
        for (int ds = 0; ds < 4; ++ds) {
            int s = tx * 4 + ds;
            float dw = dts[s], Ss_ = Sc[s];
            float4 g;
            g.x = (s <= ty*4+0) ? gacc[0][ds] * dw * __expf(Si[0] - Ss_) : 0.f;
            g.y = (s <= ty*4+1) ? gacc[1][ds] * dw * __expf(Si[1] - Ss_) : 0.f;
            g.z = (s <= ty*4+2) ? gacc[2][ds] * dw * __expf(Si[2] - Ss_) : 0.f;
            g.w = (s <= ty*4+3) ? gacc[3][ds] * dw * __expf(Si[3] - Ss_) : 0.f;
            *(float4*)&GsT[s][ty * 4] = g;
        }
    }
    __syncthreads();
    // transpose B into CsT space: Bs2[s][n]
    {
        int nn = wv * 16 + (lane >> 2);
        int s0 = (lane & 3) * 16;
        #pragma unroll
        for (int k = 0; k < 4; ++k) {
            float4 b = *(const float4*)&BsT[nn][s0 + k * 4];
            CsT[s0 + k*4 + 0][nn] = b.x;
            CsT[s0 + k*4 + 1][nn] = b.y;
            CsT[s0 + k*4 + 2][nn] = b.z;
            CsT[s0 + k*4 + 3][nn] = b.w;
        }
    }
    __syncthreads();

    // fused: Y[i][p] = sum_s G[i][s] X[s][p] ; T[p][n] = sum_s w_s X[s][p] B[s][n]
    float yacc[4][4] = {};   // [di over i=ty*4+][dp over p=tx*4+]
    float tacc[4][4] = {};   // [dq over p=ty*4+][dn over n=tx*4+]
    for (int s = 0; s < 64; ++s) {
        float4 g  = *(const float4*)&GsT[s][ty * 4];
        float4 xp = *(const float4*)&Xs[s][tx * 4];
        float4 xq = *(const float4*)&Xs[s][ty * 4];
        float4 bn = *(const float4*)&CsT[s][tx * 4];   // Bs2
        float w = ws[s];
        yacc[0][0] += g.x*xp.x; yacc[0][1] += g.x*xp.y; yacc[0][2] += g.x*xp.z; yacc[0][3] += g.x*xp.w;
        yacc[1][0] += g.y*xp.x; yacc[1][1] += g.y*xp.y; yacc[1][2] += g.y*xp.z; yacc[1][3] += g.y*xp.w;
        yacc[2][0] += g.z*xp.x; yacc[2][1] += g.z*xp.y; yacc[2][2] += g.z*xp.z; yacc[2][3] += g.z*xp.w;
        yacc[3][0] += g.w*xp.x; yacc[3][1] += g.w*xp.y; yacc[3][2] += g.w*xp.z; yacc[3][3] += g.w*xp.w;
        float wx0 = xq.x * w, wx1 = xq.y * w, wx2 = xq.z * w, wx3 = xq.w * w;
        tacc[0][0] += wx0*bn.x; tacc[0][1] += wx0*bn.y; tacc[0][2] += wx0*bn.z; tacc[0][3] += wx0*bn.w;
        tacc[1][0] += wx1*bn.x; tacc[1][1] += wx1*bn.y; tacc[1][2] += wx1*bn.z; tacc[1][3] += wx1*bn.w;
        tacc[2][0] += wx2*bn.x; tacc[2][1] += wx2*bn.y; tacc[2][2] += wx2*bn.z; tacc[2][3] += wx2*bn.w;
        tacc[3][0] += wx3*bn.x; tacc[3][1] += wx3*bn.y; tacc[3][2] += wx3*bn.z; tacc[3][3] += wx3*bn.w;
    }
    #pragma unroll
    for (int di = 0; di < 4; ++di) {
        float4 yv = {yacc[di][0], yacc[di][1], yacc[di][2], yacc[di][3]};
        *(float4*)&yintra[(size_t)(t0 + ty*4 + di) * DINNER + head * 64 + tx * 4] = yv;
    }
    float* tcb = Tc + (size_t)(head * 16 + chunk) * 4096;
    #pragma unroll
    for (int dq = 0; dq < 4; ++dq) {
        float4 tv = {tacc[dq][0], tacc[dq][1], tacc[dq][2], tacc[dq][3]};
        *(float4*)&tcb[(ty*4 + dq) * 64 + tx * 4] = tv;
    }
}

// ---------------------------------------------------------------- chunked scan B: serial carry
// block = head. In-place: T_c slot becomes H_prefix(c). h' = Q_c*h + T_c.
__global__ __launch_bounds__(256) void chunk_state_kernel(
    float* __restrict__ Tc, const float* __restrict__ Ssum)
{
    const int head = blockIdx.x;
    const int tid = threadIdx.x;
    float h[16] = {};
    float* base = Tc + (size_t)head * 16 * 4096 + tid * 16;
    for (int c = 0; c < 16; ++c) {
        float Q = __expf(Ssum[(c * 64 + 63) * 64 + head]);
        float4* p = (float4*)(base + (size_t)c * 4096);
        #pragma unroll
        for (int v = 0; v < 4; ++v) {
            float4 t = p[v];
            float4 hold = {h[v*4], h[v*4+1], h[v*4+2], h[v*4+3]};
            h[v*4+0] = h[v*4+0] * Q + t.x;
            h[v*4+1] = h[v*4+1] * Q + t.y;
            h[v*4+2] = h[v*4+2] * Q + t.z;
            h[v*4+3] = h[v*4+3] * Q + t.w;
            p[v] = hold;
        }
    }
}

// ---------------------------------------------------------------- chunked scan C: inter-chunk
// Y_inter[i][p] = exp(S_i) * sum_n Hpre[p][n] * C_i[n]
__global__ __launch_bounds__(256) void chunk_inter_kernel(
    const float* __restrict__ Hpre, const float* __restrict__ Cb,
    const float* __restrict__ Ssum, float* __restrict__ yinter)
{
    const int head  = blockIdx.x >> 4;
    const int chunk = blockIdx.x & 15;
    const int t0 = chunk * 64;
    const int tid = threadIdx.x;
    const int ty = tid >> 4, tx = tid & 15;
    const int lane = tid & 63, wv = tid >> 6;

    __shared__ __align__(16) float HsT[64][CPAD];   // [n][p]
    __shared__ __align__(16) float CsT[64][CPAD];   // [n][i]
    __shared__ float Se[64];

    const float* hb = Hpre + (size_t)(head * 16 + chunk) * 4096;
    #pragma unroll
    for (int k = 0; k < 4; ++k) {
        int n0 = wv * 16 + k * 4;
        float4 h = *(const float4*)&hb[lane * 64 + n0];
        float4 c = *(const float4*)&Cb[(t0 + lane) * 64 + n0];
        HsT[n0][lane] = h.x; HsT[n0+1][lane] = h.y; HsT[n0+2][lane] = h.z; HsT[n0+3][lane] = h.w;
        CsT[n0][lane] = c.x; CsT[n0+1][lane] = c.y; CsT[n0+2][lane] = c.z; CsT[n0+3][lane] = c.w;
    }
    if (tid < 64) Se[tid] = __expf(Ssum[(t0 + tid) * 64 + head]);
    __syncthreads();

    float acc[4][4] = {};
    for (int n = 0; n < 64; ++n) {
        float4 ci = *(const float4*)&CsT[n][ty * 4];
        float4 hp = *(const float4*)&HsT[n][tx * 4];
        acc[0][0] += ci.x*hp.x; acc[0][1] += ci.x*hp.y; acc[0][2] += ci.x*hp.z; acc[0][3] += ci.x*hp.w;
        acc[1][0] += ci.y*hp.x; acc[1][1] += ci.y*hp.y; acc[1][2] += ci.y*hp.z; acc[1][3] += ci.y*hp.w;
        acc[2][0] += ci.z*hp.x; acc[2][1] += ci.z*hp.y; acc[2][2] += ci.z*hp.z; acc[2][3] += ci.z*hp.w;
        acc[3][0] += ci.w*hp.x; acc[3][1] += ci.w*hp.y; acc[3][2] += ci.w*hp.z; acc[3][3] += ci.w*hp.w;
    }
    #pragma unroll
    for (int di = 0; di < 4; ++di) {
        float se = Se[ty * 4 + di];
        float4 yv = {acc[di][0]*se, acc[di][1]*se, acc[di][2]*se, acc[di][3]*se};
        *(float4*)&yinter[(size_t)(t0 + ty*4 + di) * DINNER + head * 64 + tx * 4] = yv;
    }
}

// ---------------------------------------------------------------- combine + gate + RMSNorm
__global__ __launch_bounds__(256) void combine_norm_kernel(
    const float* __restrict__ ypart, const float* __restrict__ x_scan,
    const float* __restrict__ zx, const float* __restrict__ Dv,
    const float* __restrict__ norm_w, ushort* __restrict__ ybf)
{
    const int t = blockIdx.x;
    const int tid = threadIdx.x;
    float yv[16];
    float ss = 0.f;
    #pragma unroll
    for (int j = 0; j < 16; ++j) {
        int i = j * 256 + tid;
        float y = ypart[(size_t)t * DINNER + i]
                + ypart[(size_t)SEQLEN * DINNER + (size_t)t * DINNER + i]
                + Dv[i >> 6] * x_scan[(size_t)t * DINNER + i];
        float z = zx[(size_t)t * DINPROJ + i];
        y *= z / (1.f + __expf(-z));
        yv[j] = y;
        ss += y * y;
    }
    #pragma unroll
    for (int off = 1; off < 64; off <<= 1) ss += __shfl_xor(ss, off, 64);
    __shared__ float red[4];
    if ((tid & 63) == 0) red[tid >> 6] = ss;
    __syncthreads();
    float total = red[0] + red[1] + red[2] + red[3];
    float scale = rsqrtf(total * (1.f / DINNER) + RMS_EPS);
    #pragma unroll
    for (int j = 0; j < 16; ++j) {
        int i = j * 256 + tid;
        ybf[(size_t)t * DINNER + i] = f2bf(yv[j] * scale * norm_w[i]);
    }
}

// ---------------------------------------------------------------- launch
extern "C" void kernel_launch(void* const* d_in, const int* in_sizes, int n_in,
                              void* d_out, int out_size, void* d_ws, size_t ws_size,
                              hipStream_t stream)
{
    const float* x       = (const float*)d_in[0];
    const float* W_in    = (const float*)d_in[1];
    const float* conv_w  = (const float*)d_in[2];
    const float* conv_b  = (const float*)d_in[3];
    const float* dt_bias = (const float*)d_in[4];
    const float* A_log   = (const float*)d_in[5];
    const float* Dv      = (const float*)d_in[6];
    const float* norm_w  = (const float*)d_in[7];
    const float* W_out   = (const float*)d_in[8];
    float* out = (float*)d_out;

    char* ws = (char*)d_ws;
    const size_t OFF_WIN  = 0;                     // 34,340,864 bf16 W_in / later ypart (32MB)
    const size_t OFF_WOUT = 34340864;              // 16,777,216 bf16 W_out
    const size_t OFF_XBF  = OFF_WOUT + 16777216;   //  4,194,304 bf16 x
    const size_t OFF_ZX   = OFF_XBF + 4194304;     // 34,340,864 f32 zxbcdt
    const size_t OFF_XSC  = OFF_ZX + 34340864;     // 16,777,216 f32 x_scan
    const size_t OFF_BB   = OFF_XSC + 16777216;
    const size_t OFF_CB   = OFF_BB + 262144;
    const size_t OFF_DT   = OFF_CB + 262144;
    const size_t OFF_DA   = OFF_DT + 262144;       // dtA
    const size_t OFF_YBF  = OFF_DA + 262144;       //  8,388,608 bf16 y
    const size_t OFF_TC   = OFF_YBF + 8388608;     // 16,777,216 f32 T/Hpre
    const size_t OFF_SS   = OFF_TC + 16777216;     //    262,144 f32 Ssum

    ushort* WinBf  = (ushort*)(ws + OFF_WIN);
    ushort* WoutBf = (ushort*)(ws + OFF_WOUT);
    ushort* xBf    = (ushort*)(ws + OFF_XBF);
    float*  zxb    = (float*)(ws + OFF_ZX);
    float*  xsc    = (float*)(ws + OFF_XSC);
    float*  Bb     = (float*)(ws + OFF_BB);
    float*  Cb     = (float*)(ws + OFF_CB);
    float*  dtb    = (float*)(ws + OFF_DT);
    float*  dtAb   = (float*)(ws + OFF_DA);
    ushort* ybf    = (ushort*)(ws + OFF_YBF);
    float*  Tc     = (float*)(ws + OFF_TC);
    float*  Ssum   = (float*)(ws + OFF_SS);
    float*  ypart  = (float*)(ws + OFF_WIN);       // alias over dead WinBf

    int n4;
    n4 = DINPROJ * DMODEL / 4;
    cvt_kernel<<<(n4 + 255) / 256, 256, 0, stream>>>(W_in, WinBf, n4);
    n4 = DMODEL * DINNER / 4;
    cvt_kernel<<<(n4 + 255) / 256, 256, 0, stream>>>(W_out, WoutBf, n4);
    n4 = SEQLEN * DMODEL / 4;
    cvt_kernel<<<(n4 + 255) / 256, 256, 0, stream>>>(x, xBf, n4);

    gemm_bf16_nt<<<dim3((DINPROJ + 127) / 128, SEQLEN / 128), 256, 0, stream>>>(
        (const __bf16*)xBf, (const __bf16*)WinBf, zxb, SEQLEN, DINPROJ, DMODEL);

    conv_dt_kernel<<<dim3(17, SEQLEN), 256, 0, stream>>>(
        zxb, conv_w, conv_b, dt_bias, A_log, xsc, Bb, Cb, dtb, dtAb);

    chunk_intra_kernel<<<1024, 256, 0, stream>>>(xsc, Bb, Cb, dtb, dtAb,
                                                 ypart, Tc, Ssum);
    chunk_state_kernel<<<64, 256, 0, stream>>>(Tc, Ssum);
    chunk_inter_kernel<<<1024, 256, 0, stream>>>(Tc, Cb, Ssum,
                                                 ypart + (size_t)SEQLEN * DINNER);

    combine_norm_kernel<<<SEQLEN, 256, 0, stream>>>(ypart, xsc, zxb, Dv, norm_w, ybf);

    gemm_bf16_nt<<<dim3(DMODEL / 128, SEQLEN / 128), 256, 0, stream>>>(
        (const __bf16*)ybf, (const __bf16*)WoutBf, out, SEQLEN, DMODEL, DINNER);
}

// Round 3
// 249.624 us; speedup vs baseline: 1.6255x; 1.1164x over previous
//
#include <hip/hip_runtime.h>
#include <hip/hip_bf16.h>
#include <stdint.h>

#define SEQLEN   1024
#define DMODEL   2048
#define DINNER   4096
#define NHEADS   64
#define HEADDIM  64
#define DSTATE   64
#define CONVDIM  4224
#define DINPROJ  8384
#define RMS_EPS  1e-5f
#define CPAD     68

typedef __attribute__((ext_vector_type(8))) __bf16 bf16x8;
typedef __attribute__((ext_vector_type(4))) float f32x4;

__device__ __forceinline__ ushort f2bf(float f) {
    uint32_t u = __float_as_uint(f);
    u += 0x7FFFu + ((u >> 16) & 1u);   // round-to-nearest-even
    return (ushort)(u >> 16);
}

__device__ __forceinline__ void gload_lds16(const void* g, void* l) {
    __builtin_amdgcn_global_load_lds(
        (const __attribute__((address_space(1))) void*)g,
        (__attribute__((address_space(3))) void*)l, 16, 0, 0);
}

// ---------------------------------------------------------------- cvt f32->bf16 (3 segments fused)
__global__ __launch_bounds__(256) void cvt3_kernel(
    const float* __restrict__ a, ushort* __restrict__ oa, int na4,
    const float* __restrict__ b, ushort* __restrict__ ob, int nb4,
    const float* __restrict__ c, ushort* __restrict__ oc, int nc4)
{
    int i = blockIdx.x * 256 + threadIdx.x;
    const float* src; ushort* dst;
    if (i < na4) { src = a; dst = oa; }
    else if (i < na4 + nb4) { i -= na4; src = b; dst = ob; }
    else { i -= na4 + nb4; if (i >= nc4) return; src = c; dst = oc; }
    float4 v = ((const float4*)src)[i];
    ushort4 o;
    o.x = f2bf(v.x); o.y = f2bf(v.y); o.z = f2bf(v.z); o.w = f2bf(v.w);
    ((ushort4*)dst)[i] = o;
}

// ---------------------------------------------------------------- 8-wave pipelined bf16 GEMM
// C[M,N] (+= split over nk) = A[M,K] * B[N,K]^T, row-major, K contiguous.
// BM=128, BN=256, BK=64. 512 thr (2x4 waves, 64x64 each). Double-buffered LDS,
// global_load_lds staged 2 tiles ahead, counted vmcnt(6), raw barriers, setprio.
__global__ __launch_bounds__(512, 2) void gemm8_bf16_nt(
    const __bf16* __restrict__ A, const __bf16* __restrict__ B,
    float* __restrict__ C, int M, int N, int K,
    int ntx, int nty, int nk, int ksteps, int swz)
{
    __shared__ __align__(16) __bf16 As[2][128 * 64];
    __shared__ __align__(16) __bf16 Bs[2][256 * 64];
    const int tid  = threadIdx.x;
    const int lane = tid & 63;
    const int wave = tid >> 6;              // 0..7
    const int wr = wave >> 2, wc = wave & 3;
    int id = blockIdx.x;
    if (swz) { int q = (ntx * nty * nk) >> 3; id = (id & 7) * q + (id >> 3); }
    const int kz  = id / (ntx * nty);
    const int rem = id % (ntx * nty);
    const int ty = rem / ntx, tx = rem % ntx;
    const int row0 = ty * 128, col0 = tx * 256;
    const int lr = lane & 15, lq = lane >> 4;
    const int rA = lane >> 3, jl = lane & 7;
    const int k0 = kz * ksteps * 64;

    // per-thread staging source pointers (advance by 64 elems per staged tile)
    const __bf16* srcA[2];
    const __bf16* srcB[4];
    int dstA[2], dstB[4];
    #pragma unroll
    for (int e = 0; e < 2; ++e) {
        int r0 = e * 64 + wave * 8;
        int r  = r0 + rA;
        int jg = jl ^ (r & 7);
        srcA[e] = A + (size_t)(row0 + r) * K + k0 + jg * 8;
        dstA[e] = r0 * 64;
    }
    #pragma unroll
    for (int e = 0; e < 4; ++e) {
        int r0 = e * 64 + wave * 8;
        int r  = r0 + rA;
        int gb = col0 + r; if (gb > N - 1) gb = N - 1;
        int jg = jl ^ (r & 7);
        srcB[e] = B + (size_t)gb * K + k0 + jg * 8;
        dstB[e] = r0 * 64;
    }

    f32x4 acc[4][4] = {};
    const int nt = ksteps;

    // prologue: stage tiles 0 and 1
    #pragma unroll
    for (int e = 0; e < 2; ++e) gload_lds16(srcA[e], &As[0][dstA[e]]);
    #pragma unroll
    for (int e = 0; e < 4; ++e) gload_lds16(srcB[e], &Bs[0][dstB[e]]);
    #pragma unroll
    for (int e = 0; e < 2; ++e) { gload_lds16(srcA[e] + 64, &As[1][dstA[e]]); srcA[e] += 128; }
    #pragma unroll
    for (int e = 0; e < 4; ++e) { gload_lds16(srcB[e] + 64, &Bs[1][dstB[e]]); srcB[e] += 128; }
    asm volatile("s_waitcnt vmcnt(6)" ::: "memory");   // tile 0 resident
    __builtin_amdgcn_s_barrier();
    asm volatile("" ::: "memory");

    for (int t = 0; t < nt; ++t) {
        const int b = t & 1;
        #pragma unroll
        for (int kk = 0; kk < 2; ++kk) {
            const int kg = kk * 4 + lq;
            bf16x8 af[4], bfr[4];
            #pragma unroll
            for (int m = 0; m < 4; ++m) {
                int r = wr * 64 + m * 16 + lr;
                af[m] = *(const bf16x8*)(&As[b][r * 64 + ((kg ^ (r & 7)) * 8)]);
            }
            #pragma unroll
            for (int n = 0; n < 4; ++n) {
                int r = wc * 64 + n * 16 + lr;
                bfr[n] = *(const bf16x8*)(&Bs[b][r * 64 + ((kg ^ (r & 7)) * 8)]);
            }
            __builtin_amdgcn_s_setprio(1);
            #pragma unroll
            for (int m = 0; m < 4; ++m)
                #pragma unroll
                for (int n = 0; n < 4; ++n)
                    acc[m][n] = __builtin_amdgcn_mfma_f32_16x16x32_bf16(af[m], bfr[n], acc[m][n], 0, 0, 0);
            __builtin_amdgcn_s_setprio(0);
        }
        __builtin_amdgcn_s_barrier();               // all waves done reading buf b
        asm volatile("" ::: "memory");
        if (t + 2 < nt) {                           // refill buf b with tile t+2
            #pragma unroll
            for (int e = 0; e < 2; ++e) { gload_lds16(srcA[e], &As[b][dstA[e]]); srcA[e] += 64; }
            #pragma unroll
            for (int e = 0; e < 4; ++e) { gload_lds16(srcB[e], &Bs[b][dstB[e]]); srcB[e] += 64; }
            asm volatile("s_waitcnt vmcnt(6)" ::: "memory");   // tile t+1 resident
        } else {
            asm volatile("s_waitcnt vmcnt(0)" ::: "memory");
        }
        __builtin_amdgcn_s_barrier();
        asm volatile("" ::: "memory");
    }

    float* Co = C + (size_t)kz * M * N;
    #pragma unroll
    for (int m = 0; m < 4; ++m)
        #pragma unroll
        for (int n = 0; n < 4; ++n) {
            int col = col0 + wc * 64 + n * 16 + lr;
            if (col < N) {
                #pragma unroll
                for (int j = 0; j < 4; ++j) {
                    int row = row0 + wr * 64 + m * 16 + lq * 4 + j;
                    Co[(size_t)row * N + col] = acc[m][n][j];
                }
            }
        }
}

// ---------------------------------------------------------------- split-K reduce (4 partials)
__global__ __launch_bounds__(256) void reduce4_kernel(
    const float* __restrict__ p, float* __restrict__ out, int n4)
{
    int i = blockIdx.x * 256 + threadIdx.x;
    if (i < n4) {
        float4 a = ((const float4*)p)[i];
        float4 b = ((const float4*)p)[i + n4];
        float4 c = ((const float4*)p)[i + 2 * (size_t)n4];
        float4 d = ((const float4*)p)[i + 3 * (size_t)n4];
        float4 o = {a.x + b.x + c.x + d.x, a.y + b.y + c.y + d.y,
                    a.z + b.z + c.z + d.z, a.w + b.w + c.w + d.w};
        ((float4*)out)[i] = o;
    }
}

// ---------------------------------------------------------------- conv + dt/dtA
__global__ __launch_bounds__(256) void conv_dt_kernel(
    const float* __restrict__ zx, const float* __restrict__ conv_w,
    const float* __restrict__ conv_b, const float* __restrict__ dt_bias,
    const float* __restrict__ A_log,
    float* __restrict__ x_scan, float* __restrict__ Bb, float* __restrict__ Cb,
    float* __restrict__ dtb, float* __restrict__ dtAb)
{
    int t = blockIdx.y;
    int c = blockIdx.x * 256 + threadIdx.x;
    if (c >= CONVDIM + NHEADS) return;
    if (c < CONVDIM) {
        float acc = conv_b[c];
        #pragma unroll
        for (int k = 0; k < 4; ++k) {
            int tt = t + k - 3;
            if (tt >= 0) acc += zx[(size_t)tt * DINPROJ + DINNER + c] * conv_w[c * 4 + k];
        }
        float s = acc / (1.f + __expf(-acc));
        if (c < DINNER)            x_scan[(size_t)t * DINNER + c] = s;
        else if (c < DINNER + 64)  Bb[t * 64 + (c - DINNER)] = s;
        else                       Cb[t * 64 + (c - DINNER - 64)] = s;
    } else {
        int h = c - CONVDIM;
        float raw = zx[(size_t)t * DINPROJ + (DINNER + CONVDIM) + h] + dt_bias[h];
        float dt = (raw > 20.f) ? raw : log1pf(__expf(raw));
        dtb[t * 64 + h]  = dt;
        dtAb[t * 64 + h] = dt * (-__expf(A_log[h]));
    }
}

// ---------------------------------------------------------------- chunked scan A: intra-chunk
__global__ __launch_bounds__(256) void chunk_intra_kernel(
    const float* __restrict__ x_scan, const float* __restrict__ Bb,
    const float* __restrict__ Cb, const float* __restrict__ dtb,
    const float* __restrict__ dtAb,
    float* __restrict__ yintra, float* __restrict__ Tc, float* __restrict__ Ssum)
{
    const int head  = blockIdx.x >> 4;
    const int chunk = blockIdx.x & 15;
    const int t0 = chunk * 64;
    const int tid = threadIdx.x;
    const int ty = tid >> 4, tx = tid & 15;
    const int lane = tid & 63, wv = tid >> 6;

    __shared__ __align__(16) float Xs [64][CPAD];
    __shared__ __align__(16) float BsT[64][CPAD];
    __shared__ __align__(16) float CsT[64][CPAD];
    __shared__ __align__(16) float GsT[64][CPAD];
    __shared__ float Sc[64], dts[64], ws[64];

    #pragma unroll
    for (int pass = 0; pass < 4; ++pass) {
        int r = pass * 16 + ty;
        *(float4*)&Xs[r][tx * 4] =
            *(const float4*)&x_scan[(size_t)(t0 + r) * DINNER + head * 64 + tx * 4];
    }
    #pragma unroll
    for (int k = 0; k < 4; ++k) {
        int n0 = wv * 16 + k * 4;
        float4 b = *(const float4*)&Bb[(t0 + lane) * 64 + n0];
        float4 c = *(const float4*)&Cb[(t0 + lane) * 64 + n0];
        BsT[n0][lane] = b.x; BsT[n0+1][lane] = b.y; BsT[n0+2][lane] = b.z; BsT[n0+3][lane] = b.w;
        CsT[n0][lane] = c.x; CsT[n0+1][lane] = c.y; CsT[n0+2][lane] = c.z; CsT[n0+3][lane] = c.w;
    }
    if (tid < 64) dts[tid] = dtb[(t0 + tid) * 64 + head];
    if (wv == 1) {
        float v = dtAb[(t0 + lane) * 64 + head];
        #pragma unroll
        for (int off = 1; off < 64; off <<= 1) {
            float u = __shfl_up(v, off, 64);
            if (lane >= off) v += u;
        }
        Sc[lane] = v;
        Ssum[(t0 + lane) * 64 + head] = v;
    }
    __syncthreads();
    if (tid < 64) ws[tid] = dts[tid] * __expf(Sc[63] - Sc[tid]);

    float gacc[4][4] = {};
    for (int n = 0; n < 64; ++n) {
        float4 ci = *(const float4*)&CsT[n][ty * 4];
        float4 bs = *(const float4*)&BsT[n][tx * 4];
        gacc[0][0] += ci.x*bs.x; gacc[0][1] += ci.x*bs.y; gacc[0][2] += ci.x*bs.z; gacc[0][3] += ci.x*bs.w;
        gacc[1][0] += ci.y*bs.x; gacc[1][1] += ci.y*bs.y; gacc[1][2] += ci.y*bs.z; gacc[1][3] += ci.y*bs.w;
        gacc[2][0] += ci.z*bs.x; gacc[2][1] += ci.z*bs.y; gacc[2][2] += ci.z*bs.z; gacc[2][3] += ci.z*bs.w;
        gacc[3][0] += ci.w*bs.x; gacc[3][1] += ci.w*bs.y; gacc[3][2] += ci.w*bs.z; gacc[3][3] += ci.w*bs.w;
    }
    {
        float Si[4];
        #pragma unroll
        for (int di = 0; di < 4; ++di) Si[di] = Sc[ty * 4 + di];
        #pragma unroll
        for (int ds = 0; ds < 4; ++ds) {
            int s = tx * 4 + ds;
            float dw = dts[s], Ss_ = Sc[s];
            float4 g;
            g.x = (s <= ty*4+0) ? gacc[0][ds] * dw * __expf(Si[0] - Ss_) : 0.f;
            g.y = (s <= ty*4+1) ? gacc[1][ds] * dw * __expf(Si[1] - Ss_) : 0.f;
            g.z = (s <= ty*4+2) ? gacc[2][ds] * dw * __expf(Si[2] - Ss_) : 0.f;
            g.w = (s <= ty*4+3) ? gacc[3][ds] * dw * __expf(Si[3] - Ss_) : 0.f;
            *(float4*)&GsT[s][ty * 4] = g;
        }
    }
    __syncthreads();
    {
        int nn = wv * 16 + (lane >> 2);
        int s0 = (lane & 3) * 16;
        #pragma unroll
        for (int k = 0; k < 4; ++k) {
            float4 b = *(const float4*)&BsT[nn][s0 + k * 4];
            CsT[s0 + k*4 + 0][nn] = b.x;
            CsT[s0 + k*4 + 1][nn] = b.y;
            CsT[s0 + k*4 + 2][nn] = b.z;
            CsT[s0 + k*4 + 3][nn] = b.w;
        }
    }
    __syncthreads();

    float yacc[4][4] = {};
    float tacc[4][4] = {};
    for (int s = 0; s < 64; ++s) {
        float4 g  = *(const float4*)&GsT[s][ty * 4];
        float4 xp = *(const float4*)&Xs[s][tx * 4];
        float4 xq = *(const float4*)&Xs[s][ty * 4];
        float4 bn = *(const float4*)&CsT[s][tx * 4];
        float w = ws[s];
        yacc[0][0] += g.x*xp.x; yacc[0][1] += g.x*xp.y; yacc[0][2] += g.x*xp.z; yacc[0][3] += g.x*xp.w;
        yacc[1][0] += g.y*xp.x; yacc[1][1] += g.y*xp.y; yacc[1][2] += g.y*xp.z; yacc[1][3] += g.y*xp.w;
        yacc[2][0] += g.z*xp.x; yacc[2][1] += g.z*xp.y; yacc[2][2] += g.z*xp.z; yacc[2][3] += g.z*xp.w;
        yacc[3][0] += g.w*xp.x; yacc[3][1] += g.w*xp.y; yacc[3][2] += g.w*xp.z; yacc[3][3] += g.w*xp.w;
        float wx0 = xq.x * w, wx1 = xq.y * w, wx2 = xq.z * w, wx3 = xq.w * w;
        tacc[0][0] += wx0*bn.x; tacc[0][1] += wx0*bn.y; tacc[0][2] += wx0*bn.z; tacc[0][3] += wx0*bn.w;
        tacc[1][0] += wx1*bn.x; tacc[1][1] += wx1*bn.y; tacc[1][2] += wx1*bn.z; tacc[1][3] += wx1*bn.w;
        tacc[2][0] += wx2*bn.x; tacc[2][1] += wx2*bn.y; tacc[2][2] += wx2*bn.z; tacc[2][3] += wx2*bn.w;
        tacc[3][0] += wx3*bn.x; tacc[3][1] += wx3*bn.y; tacc[3][2] += wx3*bn.z; tacc[3][3] += wx3*bn.w;
    }
    #pragma unroll
    for (int di = 0; di < 4; ++di) {
        float4 yv = {yacc[di][0], yacc[di][1], yacc[di][2], yacc[di][3]};
        *(float4*)&yintra[(size_t)(t0 + ty*4 + di) * DINNER + head * 64 + tx * 4] = yv;
    }
    float* tcb = Tc + (size_t)(head * 16 + chunk) * 4096;
    #pragma unroll
    for (int dq = 0; dq < 4; ++dq) {
        float4 tv = {tacc[dq][0], tacc[dq][1], tacc[dq][2], tacc[dq][3]};
        *(float4*)&tcb[(ty*4 + dq) * 64 + tx * 4] = tv;
    }
}

// ---------------------------------------------------------------- chunked scan B: serial carry
__global__ __launch_bounds__(256) void chunk_state_kernel(
    float* __restrict__ Tc, const float* __restrict__ Ssum)
{
    const int head = blockIdx.x;
    const int tid = threadIdx.x;
    float h[16] = {};
    float* base = Tc + (size_t)head * 16 * 4096 + tid * 16;
    for (int c = 0; c < 16; ++c) {
        float Q = __expf(Ssum[(c * 64 + 63) * 64 + head]);
        float4* p = (float4*)(base + (size_t)c * 4096);
        #pragma unroll
        for (int v = 0; v < 4; ++v) {
            float4 t = p[v];
            float4 hold = {h[v*4], h[v*4+1], h[v*4+2], h[v*4+3]};
            h[v*4+0] = h[v*4+0] * Q + t.x;
            h[v*4+1] = h[v*4+1] * Q + t.y;
            h[v*4+2] = h[v*4+2] * Q + t.z;
            h[v*4+3] = h[v*4+3] * Q + t.w;
            p[v] = hold;
        }
    }
}

// ---------------------------------------------------------------- chunked scan C: inter-chunk
__global__ __launch_bounds__(256) void chunk_inter_kernel(
    const float* __restrict__ Hpre, const float* __restrict__ Cb,
    const float* __restrict__ Ssum, float* __restrict__ yinter)
{
    const int head  = blockIdx.x >> 4;
    const int chunk = blockIdx.x & 15;
    const int t0 = chunk * 64;
    const int tid = threadIdx.x;
    const int ty = tid >> 4, tx = tid & 15;
    const int lane = tid & 63, wv = tid >> 6;

    __shared__ __align__(16) float HsT[64][CPAD];
    __shared__ __align__(16) float CsT[64][CPAD];
    __shared__ float Se[64];

    const float* hb = Hpre + (size_t)(head * 16 + chunk) * 4096;
    #pragma unroll
    for (int k = 0; k < 4; ++k) {
        int n0 = wv * 16 + k * 4;
        float4 h = *(const float4*)&hb[lane * 64 + n0];
        float4 c = *(const float4*)&Cb[(t0 + lane) * 64 + n0];
        HsT[n0][lane] = h.x; HsT[n0+1][lane] = h.y; HsT[n0+2][lane] = h.z; HsT[n0+3][lane] = h.w;
        CsT[n0][lane] = c.x; CsT[n0+1][lane] = c.y; CsT[n0+2][lane] = c.z; CsT[n0+3][lane] = c.w;
    }
    if (tid < 64) Se[tid] = __expf(Ssum[(t0 + tid) * 64 + head]);
    __syncthreads();

    float acc[4][4] = {};
    for (int n = 0; n < 64; ++n) {
        float4 ci = *(const float4*)&CsT[n][ty * 4];
        float4 hp = *(const float4*)&HsT[n][tx * 4];
        acc[0][0] += ci.x*hp.x; acc[0][1] += ci.x*hp.y; acc[0][2] += ci.x*hp.z; acc[0][3] += ci.x*hp.w;
        acc[1][0] += ci.y*hp.x; acc[1][1] += ci.y*hp.y; acc[1][2] += ci.y*hp.z; acc[1][3] += ci.y*hp.w;
        acc[2][0] += ci.z*hp.x; acc[2][1] += ci.z*hp.y; acc[2][2] += ci.z*hp.z; acc[2][3] += ci.z*hp.w;
        acc[3][0] += ci.w*hp.x; acc[3][1] += ci.w*hp.y; acc[3][2] += ci.w*hp.z; acc[3][3] += ci.w*hp.w;
    }
    #pragma unroll
    for (int di = 0; di < 4; ++di) {
        float se = Se[ty * 4 + di];
        float4 yv = {acc[di][0]*se, acc[di][1]*se, acc[di][2]*se, acc[di][3]*se};
        *(float4*)&yinter[(size_t)(t0 + ty*4 + di) * DINNER + head * 64 + tx * 4] = yv;
    }
}

// ---------------------------------------------------------------- combine + gate + RMSNorm
__global__ __launch_bounds__(256) void combine_norm_kernel(
    const float* __restrict__ ypart, const float* __restrict__ x_scan,
    const float* __restrict__ zx, const float* __restrict__ Dv,
    const float* __restrict__ norm_w, ushort* __restrict__ ybf)
{
    const int t = blockIdx.x;
    const int tid = threadIdx.x;
    float yv[16];
    float ss = 0.f;
    #pragma unroll
    for (int j = 0; j < 16; ++j) {
        int i = j * 256 + tid;
        float y = ypart[(size_t)t * DINNER + i]
                + ypart[(size_t)SEQLEN * DINNER + (size_t)t * DINNER + i]
                + Dv[i >> 6] * x_scan[(size_t)t * DINNER + i];
        float z = zx[(size_t)t * DINPROJ + i];
        y *= z / (1.f + __expf(-z));
        yv[j] = y;
        ss += y * y;
    }
    #pragma unroll
    for (int off = 1; off < 64; off <<= 1) ss += __shfl_xor(ss, off, 64);
    __shared__ float red[4];
    if ((tid & 63) == 0) red[tid >> 6] = ss;
    __syncthreads();
    float total = red[0] + red[1] + red[2] + red[3];
    float scale = rsqrtf(total * (1.f / DINNER) + RMS_EPS);
    #pragma unroll
    for (int j = 0; j < 16; ++j) {
        int i = j * 256 + tid;
        ybf[(size_t)t * DINNER + i] = f2bf(yv[j] * scale * norm_w[i]);
    }
}

// ---------------------------------------------------------------- launch
extern "C" void kernel_launch(void* const* d_in, const int* in_sizes, int n_in,
                              void* d_out, int out_size, void* d_ws, size_t ws_size,
                              hipStream_t stream)
{
    const float* x       = (const float*)d_in[0];
    const float* W_in    = (const float*)d_in[1];
    const float* conv_w  = (const float*)d_in[2];
    const float* conv_b  = (const float*)d_in[3];
    const float* dt_bias = (const float*)d_in[4];
    const float* A_log   = (const float*)d_in[5];
    const float* Dv      = (const float*)d_in[6];
    const float* norm_w  = (const float*)d_in[7];
    const float* W_out   = (const float*)d_in[8];
    float* out = (float*)d_out;

    char* ws = (char*)d_ws;
    const size_t OFF_WIN  = 0;                     // bf16 W_in / later ypart / later gemm2 partials
    const size_t OFF_WOUT = 34340864;
    const size_t OFF_XBF  = OFF_WOUT + 16777216;
    const size_t OFF_ZX   = OFF_XBF + 4194304;
    const size_t OFF_XSC  = OFF_ZX + 34340864;
    const size_t OFF_BB   = OFF_XSC + 16777216;
    const size_t OFF_CB   = OFF_BB + 262144;
    const size_t OFF_DT   = OFF_CB + 262144;
    const size_t OFF_DA   = OFF_DT + 262144;
    const size_t OFF_YBF  = OFF_DA + 262144;
    const size_t OFF_TC   = OFF_YBF + 8388608;
    const size_t OFF_SS   = OFF_TC + 16777216;

    ushort* WinBf  = (ushort*)(ws + OFF_WIN);
    ushort* WoutBf = (ushort*)(ws + OFF_WOUT);
    ushort* xBf    = (ushort*)(ws + OFF_XBF);
    float*  zxb    = (float*)(ws + OFF_ZX);
    float*  xsc    = (float*)(ws + OFF_XSC);
    float*  Bb     = (float*)(ws + OFF_BB);
    float*  Cb     = (float*)(ws + OFF_CB);
    float*  dtb    = (float*)(ws + OFF_DT);
    float*  dtAb   = (float*)(ws + OFF_DA);
    ushort* ybf    = (ushort*)(ws + OFF_YBF);
    float*  Tc     = (float*)(ws + OFF_TC);
    float*  Ssum   = (float*)(ws + OFF_SS);
    float*  ypart  = (float*)(ws + OFF_WIN);       // alias (WinBf dead after gemm1)
    float*  part   = (float*)(ws + OFF_WIN);       // alias (ypart dead after combine)

    const int nW4 = DINPROJ * DMODEL / 4;
    const int nO4 = DMODEL * DINNER / 4;
    const int nX4 = SEQLEN * DMODEL / 4;
    const int nAll = nW4 + nO4 + nX4;
    cvt3_kernel<<<(nAll + 255) / 256, 256, 0, stream>>>(
        W_in, WinBf, nW4, W_out, WoutBf, nO4, x, xBf, nX4);

    // gemm1: [1024 x 8384] = x[1024,2048] * W_in^T ; 33x8 tiles, no split-K
    gemm8_bf16_nt<<<264, 512, 0, stream>>>(
        (const __bf16*)xBf, (const __bf16*)WinBf, zxb,
        SEQLEN, DINPROJ, DMODEL, 33, 8, 1, DMODEL / 64, 1);

    conv_dt_kernel<<<dim3(17, SEQLEN), 256, 0, stream>>>(
        zxb, conv_w, conv_b, dt_bias, A_log, xsc, Bb, Cb, dtb, dtAb);

    chunk_intra_kernel<<<1024, 256, 0, stream>>>(xsc, Bb, Cb, dtb, dtAb,
                                                 ypart, Tc, Ssum);
    chunk_state_kernel<<<64, 256, 0, stream>>>(Tc, Ssum);
    chunk_inter_kernel<<<1024, 256, 0, stream>>>(Tc, Cb, Ssum,
                                                 ypart + (size_t)SEQLEN * DINNER);

    combine_norm_kernel<<<SEQLEN, 256, 0, stream>>>(ypart, xsc, zxb, Dv, norm_w, ybf);

    // gemm2: [1024 x 2048] = y[1024,4096] * W_out^T ; 8x8 tiles, split-K=4 -> partials
    gemm8_bf16_nt<<<256, 512, 0, stream>>>(
        (const __bf16*)ybf, (const __bf16*)WoutBf, part,
        SEQLEN, DMODEL, DINNER, 8, 8, 4, DINNER / 64 / 4, 1);

    reduce4_kernel<<<(SEQLEN * DMODEL / 4 + 255) / 256, 256, 0, stream>>>(
        part, out, SEQLEN * DMODEL / 4);
}

// Round 4
// 229.814 us; speedup vs baseline: 1.7656x; 1.0862x over previous
//
#include <hip/hip_runtime.h>
#include <hip/hip_bf16.h>
#include <stdint.h>

#define SEQLEN   1024
#define DMODEL   2048
#define DINNER   4096
#define NHEADS   64
#define HEADDIM  64
#define DSTATE   64
#define CONVDIM  4224
#define DINPROJ  8384
#define RMS_EPS  1e-5f
#define CPAD     68

typedef __attribute__((ext_vector_type(8))) __bf16 bf16x8;
typedef __attribute__((ext_vector_type(4))) float f32x4;

__device__ __forceinline__ ushort f2bf(float f) {
    uint32_t u = __float_as_uint(f);
    u += 0x7FFFu + ((u >> 16) & 1u);   // round-to-nearest-even
    return (ushort)(u >> 16);
}

__device__ __forceinline__ void gload_lds16(const void* g, void* l) {
    __builtin_amdgcn_global_load_lds(
        (const __attribute__((address_space(1))) void*)g,
        (__attribute__((address_space(3))) void*)l, 16, 0, 0);
}

// ---------------------------------------------------------------- cvt f32->bf16 (3 segments fused)
__global__ __launch_bounds__(256) void cvt3_kernel(
    const float* __restrict__ a, ushort* __restrict__ oa, int na4,
    const float* __restrict__ b, ushort* __restrict__ ob, int nb4,
    const float* __restrict__ c, ushort* __restrict__ oc, int nc4)
{
    int i = blockIdx.x * 256 + threadIdx.x;
    const float* src; ushort* dst;
    if (i < na4) { src = a; dst = oa; }
    else if (i < na4 + nb4) { i -= na4; src = b; dst = ob; }
    else { i -= na4 + nb4; if (i >= nc4) return; src = c; dst = oc; }
    float4 v = ((const float4*)src)[i];
    ushort4 o;
    o.x = f2bf(v.x); o.y = f2bf(v.y); o.z = f2bf(v.z); o.w = f2bf(v.w);
    ((ushort4*)dst)[i] = o;
}

// ---------------------------------------------------------------- 4-wave pipelined bf16 GEMM
// C[M,N] (nk partials) = A[M,K]*B[N,K]^T, row-major. BM=BN=128, BK=64, 256 thr
// (2x2 waves, 64x64 each). Double-buffered LDS (64KB -> 2 blocks/CU for
// cross-block stall overlap), global_load_lds staged 2 tiles ahead, counted
// vmcnt(8) (never 0 mid-loop), raw barriers, setprio around MFMA cluster.
__global__ __launch_bounds__(256, 2) void gemm4_bf16_nt(
    const __bf16* __restrict__ A, const __bf16* __restrict__ B,
    float* __restrict__ C, int M, int N, int K,
    int ntx, int nty, int nk, int ksteps, int swz)
{
    __shared__ __align__(16) __bf16 As[2][128 * 64];
    __shared__ __align__(16) __bf16 Bs[2][128 * 64];
    const int tid  = threadIdx.x;
    const int lane = tid & 63;
    const int wave = tid >> 6;              // 0..3
    const int wr = wave >> 1, wc = wave & 1;
    int id = blockIdx.x;
    if (swz) { int q = (ntx * nty * nk) >> 3; id = (id & 7) * q + (id >> 3); }
    const int kz  = id / (ntx * nty);
    const int rem = id % (ntx * nty);
    const int ty = rem / ntx, tx = rem % ntx;
    const int row0 = ty * 128, col0 = tx * 128;
    const int lr = lane & 15, lq = lane >> 4;
    const int rA = lane >> 3, jl = lane & 7;
    const int k0 = kz * ksteps * 64;

    // staging: 4 waves x 4 chunks x 8 rows = 128 rows of A and of B per K-tile
    const __bf16* srcA[4];
    const __bf16* srcB[4];
    int dstAB[4];
    #pragma unroll
    for (int e = 0; e < 4; ++e) {
        int r0 = (wave * 4 + e) * 8;
        int r  = r0 + rA;
        int jg = jl ^ (r & 7);
        srcA[e] = A + (size_t)(row0 + r) * K + k0 + jg * 8;
        int gb = col0 + r; if (gb > N - 1) gb = N - 1;
        srcB[e] = B + (size_t)gb * K + k0 + jg * 8;
        dstAB[e] = r0 * 64;
    }

    f32x4 acc[4][4] = {};
    const int nt = ksteps;

    // prologue: stage tiles 0 and 1 (16 loads in flight)
    #pragma unroll
    for (int e = 0; e < 4; ++e) {
        gload_lds16(srcA[e], &As[0][dstAB[e]]);
        gload_lds16(srcB[e], &Bs[0][dstAB[e]]);
    }
    #pragma unroll
    for (int e = 0; e < 4; ++e) {
        gload_lds16(srcA[e] + 64, &As[1][dstAB[e]]);
        gload_lds16(srcB[e] + 64, &Bs[1][dstAB[e]]);
        srcA[e] += 128; srcB[e] += 128;
    }
    asm volatile("s_waitcnt vmcnt(8)" ::: "memory");   // tile 0 resident
    __builtin_amdgcn_s_barrier();
    asm volatile("" ::: "memory");

    for (int t = 0; t < nt; ++t) {
        const int b = t & 1;
        #pragma unroll
        for (int kk = 0; kk < 2; ++kk) {
            const int kg = kk * 4 + lq;
            bf16x8 af[4], bfr[4];
            #pragma unroll
            for (int m = 0; m < 4; ++m) {
                int r = wr * 64 + m * 16 + lr;
                af[m] = *(const bf16x8*)(&As[b][r * 64 + ((kg ^ (r & 7)) * 8)]);
            }
            #pragma unroll
            for (int n = 0; n < 4; ++n) {
                int r = wc * 64 + n * 16 + lr;
                bfr[n] = *(const bf16x8*)(&Bs[b][r * 64 + ((kg ^ (r & 7)) * 8)]);
            }
            __builtin_amdgcn_s_setprio(1);
            #pragma unroll
            for (int m = 0; m < 4; ++m)
                #pragma unroll
                for (int n = 0; n < 4; ++n)
                    acc[m][n] = __builtin_amdgcn_mfma_f32_16x16x32_bf16(af[m], bfr[n], acc[m][n], 0, 0, 0);
            __builtin_amdgcn_s_setprio(0);
        }
        __builtin_amdgcn_s_barrier();               // all waves done reading buf b
        asm volatile("" ::: "memory");
        if (t + 2 < nt) {                           // refill buf b with tile t+2
            #pragma unroll
            for (int e = 0; e < 4; ++e) {
                gload_lds16(srcA[e], &As[b][dstAB[e]]);
                gload_lds16(srcB[e], &Bs[b][dstAB[e]]);
                srcA[e] += 64; srcB[e] += 64;
            }
            asm volatile("s_waitcnt vmcnt(8)" ::: "memory");   // tile t+1 resident
        } else {
            asm volatile("s_waitcnt vmcnt(0)" ::: "memory");
        }
        __builtin_amdgcn_s_barrier();
        asm volatile("" ::: "memory");
    }

    float* Co = C + (size_t)kz * M * N;
    #pragma unroll
    for (int m = 0; m < 4; ++m)
        #pragma unroll
        for (int n = 0; n < 4; ++n) {
            int col = col0 + wc * 64 + n * 16 + lr;
            if (col < N) {
                #pragma unroll
                for (int j = 0; j < 4; ++j) {
                    int row = row0 + wr * 64 + m * 16 + lq * 4 + j;
                    Co[(size_t)row * N + col] = acc[m][n][j];
                }
            }
        }
}

// ---------------------------------------------------------------- split-K reduce (4 partials)
__global__ __launch_bounds__(256) void reduce4_kernel(
    const float* __restrict__ p, float* __restrict__ out, int n4)
{
    int i = blockIdx.x * 256 + threadIdx.x;
    if (i < n4) {
        float4 a = ((const float4*)p)[i];
        float4 b = ((const float4*)p)[i + n4];
        float4 c = ((const float4*)p)[i + 2 * (size_t)n4];
        float4 d = ((const float4*)p)[i + 3 * (size_t)n4];
        float4 o = {a.x + b.x + c.x + d.x, a.y + b.y + c.y + d.y,
                    a.z + b.z + c.z + d.z, a.w + b.w + c.w + d.w};
        ((float4*)out)[i] = o;
    }
}

// ---------------------------------------------------------------- conv + dt/dtA
__global__ __launch_bounds__(256) void conv_dt_kernel(
    const float* __restrict__ zx, const float* __restrict__ conv_w,
    const float* __restrict__ conv_b, const float* __restrict__ dt_bias,
    const float* __restrict__ A_log,
    float* __restrict__ x_scan, float* __restrict__ Bb, float* __restrict__ Cb,
    float* __restrict__ dtb, float* __restrict__ dtAb)
{
    int t = blockIdx.y;
    int c = blockIdx.x * 256 + threadIdx.x;
    if (c >= CONVDIM + NHEADS) return;
    if (c < CONVDIM) {
        float acc = conv_b[c];
        #pragma unroll
        for (int k = 0; k < 4; ++k) {
            int tt = t + k - 3;
            if (tt >= 0) acc += zx[(size_t)tt * DINPROJ + DINNER + c] * conv_w[c * 4 + k];
        }
        float s = acc / (1.f + __expf(-acc));
        if (c < DINNER)            x_scan[(size_t)t * DINNER + c] = s;
        else if (c < DINNER + 64)  Bb[t * 64 + (c - DINNER)] = s;
        else                       Cb[t * 64 + (c - DINNER - 64)] = s;
    } else {
        int h = c - CONVDIM;
        float raw = zx[(size_t)t * DINPROJ + (DINNER + CONVDIM) + h] + dt_bias[h];
        float dt = (raw > 20.f) ? raw : log1pf(__expf(raw));
        dtb[t * 64 + h]  = dt;
        dtAb[t * 64 + h] = dt * (-__expf(A_log[h]));
    }
}

// ---------------------------------------------------------------- chunked scan A: intra-chunk
__global__ __launch_bounds__(256) void chunk_intra_kernel(
    const float* __restrict__ x_scan, const float* __restrict__ Bb,
    const float* __restrict__ Cb, const float* __restrict__ dtb,
    const float* __restrict__ dtAb,
    float* __restrict__ yintra, float* __restrict__ Tc, float* __restrict__ Ssum)
{
    const int head  = blockIdx.x >> 4;
    const int chunk = blockIdx.x & 15;
    const int t0 = chunk * 64;
    const int tid = threadIdx.x;
    const int ty = tid >> 4, tx = tid & 15;
    const int lane = tid & 63, wv = tid >> 6;

    __shared__ __align__(16) float Xs [64][CPAD];
    __shared__ __align__(16) float BsT[64][CPAD];
    __shared__ __align__(16) float CsT[64][CPAD];
    __shared__ __align__(16) float GsT[64][CPAD];
    __shared__ float Sc[64], dts[64], ws[64];

    #pragma unroll
    for (int pass = 0; pass < 4; ++pass) {
        int r = pass * 16 + ty;
        *(float4*)&Xs[r][tx * 4] =
            *(const float4*)&x_scan[(size_t)(t0 + r) * DINNER + head * 64 + tx * 4];
    }
    #pragma unroll
    for (int k = 0; k < 4; ++k) {
        int n0 = wv * 16 + k * 4;
        float4 b = *(const float4*)&Bb[(t0 + lane) * 64 + n0];
        float4 c = *(const float4*)&Cb[(t0 + lane) * 64 + n0];
        BsT[n0][lane] = b.x; BsT[n0+1][lane] = b.y; BsT[n0+2][lane] = b.z; BsT[n0+3][lane] = b.w;
        CsT[n0][lane] = c.x; CsT[n0+1][lane] = c.y; CsT[n0+2][lane] = c.z; CsT[n0+3][lane] = c.w;
    }
    if (tid < 64) dts[tid] = dtb[(t0 + tid) * 64 + head];
    if (wv == 1) {
        float v = dtAb[(t0 + lane) * 64 + head];
        #pragma unroll
        for (int off = 1; off < 64; off <<= 1) {
            float u = __shfl_up(v, off, 64);
            if (lane >= off) v += u;
        }
        Sc[lane] = v;
        Ssum[(t0 + lane) * 64 + head] = v;
    }
    __syncthreads();
    if (tid < 64) ws[tid] = dts[tid] * __expf(Sc[63] - Sc[tid]);

    float gacc[4][4] = {};
    for (int n = 0; n < 64; ++n) {
        float4 ci = *(const float4*)&CsT[n][ty * 4];
        float4 bs = *(const float4*)&BsT[n][tx * 4];
        gacc[0][0] += ci.x*bs.x; gacc[0][1] += ci.x*bs.y; gacc[0][2] += ci.x*bs.z; gacc[0][3] += ci.x*bs.w;
        gacc[1][0] += ci.y*bs.x; gacc[1][1] += ci.y*bs.y; gacc[1][2] += ci.y*bs.z; gacc[1][3] += ci.y*bs.w;
        gacc[2][0] += ci.z*bs.x; gacc[2][1] += ci.z*bs.y; gacc[2][2] += ci.z*bs.z; gacc[2][3] += ci.z*bs.w;
        gacc[3][0] += ci.w*bs.x; gacc[3][1] += ci.w*bs.y; gacc[3][2] += ci.w*bs.z; gacc[3][3] += ci.w*bs.w;
    }
    {
        float Si[4];
        #pragma unroll
        for (int di = 0; di < 4; ++di) Si[di] = Sc[ty * 4 + di];
        #pragma unroll
        for (int ds = 0; ds < 4; ++ds) {
            int s = tx * 4 + ds;
            float dw = dts[s], Ss_ = Sc[s];
            float4 g;
            g.x = (s <= ty*4+0) ? gacc[0][ds] * dw * __expf(Si[0] - Ss_) : 0.f;
            g.y = (s <= ty*4+1) ? gacc[1][ds] * dw * __expf(Si[1] - Ss_) : 0.f;
            g.z = (s <= ty*4+2) ? gacc[2][ds] * dw * __expf(Si[2] - Ss_) : 0.f;
            g.w = (s <= ty*4+3) ? gacc[3][ds] * dw * __expf(Si[3] - Ss_) : 0.f;
            *(float4*)&GsT[s][ty * 4] = g;
        }
    }
    __syncthreads();
    {
        int nn = wv * 16 + (lane >> 2);
        int s0 = (lane & 3) * 16;
        #pragma unroll
        for (int k = 0; k < 4; ++k) {
            float4 b = *(const float4*)&BsT[nn][s0 + k * 4];
            CsT[s0 + k*4 + 0][nn] = b.x;
            CsT[s0 + k*4 + 1][nn] = b.y;
            CsT[s0 + k*4 + 2][nn] = b.z;
            CsT[s0 + k*4 + 3][nn] = b.w;
        }
    }
    __syncthreads();

    float yacc[4][4] = {};
    float tacc[4][4] = {};
    for (int s = 0; s < 64; ++s) {
        float4 g  = *(const float4*)&GsT[s][ty * 4];
        float4 xp = *(const float4*)&Xs[s][tx * 4];
        float4 xq = *(const float4*)&Xs[s][ty * 4];
        float4 bn = *(const float4*)&CsT[s][tx * 4];
        float w = ws[s];
        yacc[0][0] += g.x*xp.x; yacc[0][1] += g.x*xp.y; yacc[0][2] += g.x*xp.z; yacc[0][3] += g.x*xp.w;
        yacc[1][0] += g.y*xp.x; yacc[1][1] += g.y*xp.y; yacc[1][2] += g.y*xp.z; yacc[1][3] += g.y*xp.w;
        yacc[2][0] += g.z*xp.x; yacc[2][1] += g.z*xp.y; yacc[2][2] += g.z*xp.z; yacc[2][3] += g.z*xp.w;
        yacc[3][0] += g.w*xp.x; yacc[3][1] += g.w*xp.y; yacc[3][2] += g.w*xp.z; yacc[3][3] += g.w*xp.w;
        float wx0 = xq.x * w, wx1 = xq.y * w, wx2 = xq.z * w, wx3 = xq.w * w;
        tacc[0][0] += wx0*bn.x; tacc[0][1] += wx0*bn.y; tacc[0][2] += wx0*bn.z; tacc[0][3] += wx0*bn.w;
        tacc[1][0] += wx1*bn.x; tacc[1][1] += wx1*bn.y; tacc[1][2] += wx1*bn.z; tacc[1][3] += wx1*bn.w;
        tacc[2][0] += wx2*bn.x; tacc[2][1] += wx2*bn.y; tacc[2][2] += wx2*bn.z; tacc[2][3] += wx2*bn.w;
        tacc[3][0] += wx3*bn.x; tacc[3][1] += wx3*bn.y; tacc[3][2] += wx3*bn.z; tacc[3][3] += wx3*bn.w;
    }
    #pragma unroll
    for (int di = 0; di < 4; ++di) {
        float4 yv = {yacc[di][0], yacc[di][1], yacc[di][2], yacc[di][3]};
        *(float4*)&yintra[(size_t)(t0 + ty*4 + di) * DINNER + head * 64 + tx * 4] = yv;
    }
    float* tcb = Tc + (size_t)(head * 16 + chunk) * 4096;
    #pragma unroll
    for (int dq = 0; dq < 4; ++dq) {
        float4 tv = {tacc[dq][0], tacc[dq][1], tacc[dq][2], tacc[dq][3]};
        *(float4*)&tcb[(ty*4 + dq) * 64 + tx * 4] = tv;
    }
}

// ---------------------------------------------------------------- chunked scan B: serial carry
__global__ __launch_bounds__(256) void chunk_state_kernel(
    float* __restrict__ Tc, const float* __restrict__ Ssum)
{
    const int head = blockIdx.x;
    const int tid = threadIdx.x;
    float h[16] = {};
    float* base = Tc + (size_t)head * 16 * 4096 + tid * 16;
    for (int c = 0; c < 16; ++c) {
        float Q = __expf(Ssum[(c * 64 + 63) * 64 + head]);
        float4* p = (float4*)(base + (size_t)c * 4096);
        #pragma unroll
        for (int v = 0; v < 4; ++v) {
            float4 t = p[v];
            float4 hold = {h[v*4], h[v*4+1], h[v*4+2], h[v*4+3]};
            h[v*4+0] = h[v*4+0] * Q + t.x;
            h[v*4+1] = h[v*4+1] * Q + t.y;
            h[v*4+2] = h[v*4+2] * Q + t.z;
            h[v*4+3] = h[v*4+3] * Q + t.w;
            p[v] = hold;
        }
    }
}

// ---------------------------------------------------------------- chunked scan C: inter-chunk
__global__ __launch_bounds__(256) void chunk_inter_kernel(
    const float* __restrict__ Hpre, const float* __restrict__ Cb,
    const float* __restrict__ Ssum, float* __restrict__ yinter)
{
    const int head  = blockIdx.x >> 4;
    const int chunk = blockIdx.x & 15;
    const int t0 = chunk * 64;
    const int tid = threadIdx.x;
    const int ty = tid >> 4, tx = tid & 15;
    const int lane = tid & 63, wv = tid >> 6;

    __shared__ __align__(16) float HsT[64][CPAD];
    __shared__ __align__(16) float CsT[64][CPAD];
    __shared__ float Se[64];

    const float* hb = Hpre + (size_t)(head * 16 + chunk) * 4096;
    #pragma unroll
    for (int k = 0; k < 4; ++k) {
        int n0 = wv * 16 + k * 4;
        float4 h = *(const float4*)&hb[lane * 64 + n0];
        float4 c = *(const float4*)&Cb[(t0 + lane) * 64 + n0];
        HsT[n0][lane] = h.x; HsT[n0+1][lane] = h.y; HsT[n0+2][lane] = h.z; HsT[n0+3][lane] = h.w;
        CsT[n0][lane] = c.x; CsT[n0+1][lane] = c.y; CsT[n0+2][lane] = c.z; CsT[n0+3][lane] = c.w;
    }
    if (tid < 64) Se[tid] = __expf(Ssum[(t0 + tid) * 64 + head]);
    __syncthreads();

    float acc[4][4] = {};
    for (int n = 0; n < 64; ++n) {
        float4 ci = *(const float4*)&CsT[n][ty * 4];
        float4 hp = *(const float4*)&HsT[n][tx * 4];
        acc[0][0] += ci.x*hp.x; acc[0][1] += ci.x*hp.y; acc[0][2] += ci.x*hp.z; acc[0][3] += ci.x*hp.w;
        acc[1][0] += ci.y*hp.x; acc[1][1] += ci.y*hp.y; acc[1][2] += ci.y*hp.z; acc[1][3] += ci.y*hp.w;
        acc[2][0] += ci.z*hp.x; acc[2][1] += ci.z*hp.y; acc[2][2] += ci.z*hp.z; acc[2][3] += ci.z*hp.w;
        acc[3][0] += ci.w*hp.x; acc[3][1] += ci.w*hp.y; acc[3][2] += ci.w*hp.z; acc[3][3] += ci.w*hp.w;
    }
    #pragma unroll
    for (int di = 0; di < 4; ++di) {
        float se = Se[ty * 4 + di];
        float4 yv = {acc[di][0]*se, acc[di][1]*se, acc[di][2]*se, acc[di][3]*se};
        *(float4*)&yinter[(size_t)(t0 + ty*4 + di) * DINNER + head * 64 + tx * 4] = yv;
    }
}

// ---------------------------------------------------------------- combine + gate + RMSNorm
__global__ __launch_bounds__(256) void combine_norm_kernel(
    const float* __restrict__ ypart, const float* __restrict__ x_scan,
    const float* __restrict__ zx, const float* __restrict__ Dv,
    const float* __restrict__ norm_w, ushort* __restrict__ ybf)
{
    const int t = blockIdx.x;
    const int tid = threadIdx.x;
    float yv[16];
    float ss = 0.f;
    #pragma unroll
    for (int j = 0; j < 16; ++j) {
        int i = j * 256 + tid;
        float y = ypart[(size_t)t * DINNER + i]
                + ypart[(size_t)SEQLEN * DINNER + (size_t)t * DINNER + i]
                + Dv[i >> 6] * x_scan[(size_t)t * DINNER + i];
        float z = zx[(size_t)t * DINPROJ + i];
        y *= z / (1.f + __expf(-z));
        yv[j] = y;
        ss += y * y;
    }
    #pragma unroll
    for (int off = 1; off < 64; off <<= 1) ss += __shfl_xor(ss, off, 64);
    __shared__ float red[4];
    if ((tid & 63) == 0) red[tid >> 6] = ss;
    __syncthreads();
    float total = red[0] + red[1] + red[2] + red[3];
    float scale = rsqrtf(total * (1.f / DINNER) + RMS_EPS);
    #pragma unroll
    for (int j = 0; j < 16; ++j) {
        int i = j * 256 + tid;
        ybf[(size_t)t * DINNER + i] = f2bf(yv[j] * scale * norm_w[i]);
    }
}

// ---------------------------------------------------------------- launch
extern "C" void kernel_launch(void* const* d_in, const int* in_sizes, int n_in,
                              void* d_out, int out_size, void* d_ws, size_t ws_size,
                              hipStream_t stream)
{
    const float* x       = (const float*)d_in[0];
    const float* W_in    = (const float*)d_in[1];
    const float* conv_w  = (const float*)d_in[2];
    const float* conv_b  = (const float*)d_in[3];
    const float* dt_bias = (const float*)d_in[4];
    const float* A_log   = (const float*)d_in[5];
    const float* Dv      = (const float*)d_in[6];
    const float* norm_w  = (const float*)d_in[7];
    const float* W_out   = (const float*)d_in[8];
    float* out = (float*)d_out;

    char* ws = (char*)d_ws;
    const size_t OFF_WIN  = 0;                     // bf16 W_in / later ypart / later gemm2 partials
    const size_t OFF_WOUT = 34340864;
    const size_t OFF_XBF  = OFF_WOUT + 16777216;
    const size_t OFF_ZX   = OFF_XBF + 4194304;
    const size_t OFF_XSC  = OFF_ZX + 34340864;
    const size_t OFF_BB   = OFF_XSC + 16777216;
    const size_t OFF_CB   = OFF_BB + 262144;
    const size_t OFF_DT   = OFF_CB + 262144;
    const size_t OFF_DA   = OFF_DT + 262144;
    const size_t OFF_YBF  = OFF_DA + 262144;
    const size_t OFF_TC   = OFF_YBF + 8388608;
    const size_t OFF_SS   = OFF_TC + 16777216;

    ushort* WinBf  = (ushort*)(ws + OFF_WIN);
    ushort* WoutBf = (ushort*)(ws + OFF_WOUT);
    ushort* xBf    = (ushort*)(ws + OFF_XBF);
    float*  zxb    = (float*)(ws + OFF_ZX);
    float*  xsc    = (float*)(ws + OFF_XSC);
    float*  Bb     = (float*)(ws + OFF_BB);
    float*  Cb     = (float*)(ws + OFF_CB);
    float*  dtb    = (float*)(ws + OFF_DT);
    float*  dtAb   = (float*)(ws + OFF_DA);
    ushort* ybf    = (ushort*)(ws + OFF_YBF);
    float*  Tc     = (float*)(ws + OFF_TC);
    float*  Ssum   = (float*)(ws + OFF_SS);
    float*  ypart  = (float*)(ws + OFF_WIN);       // alias (WinBf dead after gemm1)
    float*  part   = (float*)(ws + OFF_WIN);       // alias (ypart dead after combine)

    const int nW4 = DINPROJ * DMODEL / 4;
    const int nO4 = DMODEL * DINNER / 4;
    const int nX4 = SEQLEN * DMODEL / 4;
    const int nAll = nW4 + nO4 + nX4;
    cvt3_kernel<<<(nAll + 255) / 256, 256, 0, stream>>>(
        W_in, WinBf, nW4, W_out, WoutBf, nO4, x, xBf, nX4);

    // gemm1: [1024 x 8384] = x[1024,2048] * W_in^T ; 66x8 = 528 blocks (2/CU)
    gemm4_bf16_nt<<<528, 256, 0, stream>>>(
        (const __bf16*)xBf, (const __bf16*)WinBf, zxb,
        SEQLEN, DINPROJ, DMODEL, 66, 8, 1, DMODEL / 64, 1);

    conv_dt_kernel<<<dim3(17, SEQLEN), 256, 0, stream>>>(
        zxb, conv_w, conv_b, dt_bias, A_log, xsc, Bb, Cb, dtb, dtAb);

    chunk_intra_kernel<<<1024, 256, 0, stream>>>(xsc, Bb, Cb, dtb, dtAb,
                                                 ypart, Tc, Ssum);
    chunk_state_kernel<<<64, 256, 0, stream>>>(Tc, Ssum);
    chunk_inter_kernel<<<1024, 256, 0, stream>>>(Tc, Cb, Ssum,
                                                 ypart + (size_t)SEQLEN * DINNER);

    combine_norm_kernel<<<SEQLEN, 256, 0, stream>>>(ypart, xsc, zxb, Dv, norm_w, ybf);

    // gemm2: [1024 x 2048] = y[1024,4096] * W_out^T ; 16x8 tiles, split-K=4 -> 512 blocks (2/CU)
    gemm4_bf16_nt<<<512, 256, 0, stream>>>(
        (const __bf16*)ybf, (const __bf16*)WoutBf, part,
        SEQLEN, DMODEL, DINNER, 16, 8, 4, DINNER / 64 / 4, 1);

    reduce4_kernel<<<(SEQLEN * DMODEL / 4 + 255) / 256, 256, 0, stream>>>(
        part, out, SEQLEN * DMODEL / 4);
}